// Round 8
// baseline (43.815 us; speedup 1.0000x reference)
//
#include <hip/hip_runtime.h>
#include <stdint.h>

#define B_DIM 2048
#define K_DIM 2048
#define N_PACK 4096

typedef int v4i __attribute__((ext_vector_type(4)));

__device__ __forceinline__ float fqf(float x) {
    float q = rintf(x * 32.0f);
    q = fminf(fmaxf(q, -128.0f), 127.0f);
    return q * 0.03125f;
}
__device__ __forceinline__ int q8i(float x) {
    float q = rintf(x * 32.0f);
    q = fminf(fmaxf(q, -128.0f), 127.0f);
    return (int)q;
}
// fast sigmoid/tanh: v_exp_f32 + fast div; saturate gracefully at +-inf.
__device__ __forceinline__ float fsigm(float x) {
    return __fdividef(1.0f, 1.0f + __expf(-x));
}
__device__ __forceinline__ float ftanh(float x) {
    return __fdividef(2.0f, 1.0f + __expf(-2.0f * x)) - 1.0f;
}

// Quantize + pack. R16: Xh path = R15 (16B stores); W path = R10-proven
// fragment packing so the GEMM loads B straight from global, bypassing LDS
// (attacks the fitted LDS-traffic wall ~40-45 B/cyc/CU).
// Wq2 layout: col-group c0 (16 packed cols), 64B-k-chunk c (0..31):
//   byte c0*32768 + c*1024 + l*16 holds B[c0*16 + (l&15)][c*64 + (l>>4)*16 ..+16]
// == the verified 16x16x64 i8 B-fragment map -> wave b-frag load is ONE
// coalesced global_load_dwordx4 (1 KB), bitwise-identical to R8's LDS read.
//  blocks [0, 1024)   : Xh rows 2b,2b+1 -> Xhq int8
//  blocks [1024,1280) : W 16-row groups -> Wq2 fragment-packed (LDS transpose)
//  block  1280        : bias -> bqp[j*4 + gate]
__global__ __launch_bounds__(256) void quant_pack(
    const float* __restrict__ X, const float* __restrict__ hI,
    const float* __restrict__ W, const float* __restrict__ bias,
    int8_t* __restrict__ Xhq, int8_t* __restrict__ Wq2, float* __restrict__ bqp)
{
    __shared__ __align__(16) char lds[16 * 2064];   // W-path transpose buffer
    const int bid = blockIdx.x;
    const int t = threadIdx.x;
    if (bid < 1024) {
        const int m = bid * 2 + (t >> 7);        // 2 rows per block
        const int k0 = (t & 127) * 16;           // 1024%16==0: never straddles X/h
        const float* src = (k0 < 1024) ? (X + (size_t)m * 1024 + k0)
                                       : (hI + (size_t)m * 1024 + (k0 - 1024));
        float4 v0 = *(const float4*)src;
        float4 v1 = *(const float4*)(src + 4);
        float4 v2 = *(const float4*)(src + 8);
        float4 v3 = *(const float4*)(src + 12);
        union { int8_t c[16]; v4i q; } u;
        u.c[0]  = (int8_t)q8i(v0.x); u.c[1]  = (int8_t)q8i(v0.y);
        u.c[2]  = (int8_t)q8i(v0.z); u.c[3]  = (int8_t)q8i(v0.w);
        u.c[4]  = (int8_t)q8i(v1.x); u.c[5]  = (int8_t)q8i(v1.y);
        u.c[6]  = (int8_t)q8i(v1.z); u.c[7]  = (int8_t)q8i(v1.w);
        u.c[8]  = (int8_t)q8i(v2.x); u.c[9]  = (int8_t)q8i(v2.y);
        u.c[10] = (int8_t)q8i(v2.z); u.c[11] = (int8_t)q8i(v2.w);
        u.c[12] = (int8_t)q8i(v3.x); u.c[13] = (int8_t)q8i(v3.y);
        u.c[14] = (int8_t)q8i(v3.z); u.c[15] = (int8_t)q8i(v3.w);
        *(v4i*)(Xhq + (size_t)m * K_DIM + k0) = u.q;
    } else if (bid < 1280) {
        const int c0 = bid - 1024;               // col-group: packed cols [c0*16, +16)
        // phase 1: quantize 16 source rows into LDS (coalesced reads).
        // packed p = c0*16 + pi -> gate = pi&3, j = c0*4 + (pi>>2)
        for (int pi = 0; pi < 16; ++pi) {
            const int r = (pi & 3) * 1024 + c0 * 4 + (pi >> 2);
            const float* src = W + (size_t)r * K_DIM + t * 8;
            float4 v0 = *(const float4*)src;
            float4 v1 = *(const float4*)(src + 4);
            union { int8_t c[8]; int64_t ll; } u;
            u.c[0] = (int8_t)q8i(v0.x); u.c[1] = (int8_t)q8i(v0.y);
            u.c[2] = (int8_t)q8i(v0.z); u.c[3] = (int8_t)q8i(v0.w);
            u.c[4] = (int8_t)q8i(v1.x); u.c[5] = (int8_t)q8i(v1.y);
            u.c[6] = (int8_t)q8i(v1.z); u.c[7] = (int8_t)q8i(v1.w);
            *(int64_t*)(lds + pi * 2064 + t * 8) = u.ll;
        }
        __syncthreads();
        // phase 2: emit 32 chunks of 1KB, fragment-ordered, coalesced writes.
        const int w = t >> 6, l = t & 63;
        #pragma unroll
        for (int rd = 0; rd < 8; ++rd) {
            const int c = rd * 4 + w;            // 64B-k-chunk id, 0..31
            v4i val = *(const v4i*)(lds + (l & 15) * 2064 + c * 64 + (l >> 4) * 16);
            *(v4i*)(Wq2 + ((size_t)c0 << 15) + c * 1024 + l * 16) = val;
        }
    } else {
        for (int idx = t; idx < N_PACK; idx += 256) {
            const int gate = idx >> 10, j = idx & 1023;
            bqp[(j << 2) | gate] = fqf(bias[idx]);
        }
    }
}

// GEMM C[2048][4096p] = Xhq @ Wq2 (int8 -> i32, exact), fused LSTM epilogue.
// R16 = R8's exact proven skeleton (grid 512 + XCD swizzle, 512 thr, 8 waves
// 2m x 4n of 64x32, BK=128, 2-barrier counted-vmcnt loop, A chunk-XOR LDS
// swizzle, LDS-C epilogue, 2 blocks/CU) with ONE change: B comes from global
// (fragment-packed Wq2, reg double-buffered) instead of LDS.
//   Why: fitted wall = total LDS traffic (~40-45 B/cyc/CU: R8 2304r+2048w,
//   R13, R14 all fit). Dropping B halves writes and cuts reads 33% ->
//   per-step ~2560 cyc vs R8's ~4350. R10's global-B crater was confounded
//   (1-domain/2-wave slow cell + BN=256 L1 thrash + bank conflicts); this
//   is the clean test at the proven-fast operating point.
//   Per-iter VMEM: 2 A-gll + 4 B-loads -> steady vmcnt(6) (never 0 mid-loop).
__global__ __launch_bounds__(512, 4) void lstm_gemm(
    const int8_t* __restrict__ Xhq, const int8_t* __restrict__ Wq2,
    const float* __restrict__ bqp, const float* __restrict__ cin,
    float* __restrict__ hout, float* __restrict__ cout_)
{
    __shared__ __align__(16) char raw[33792];   // A dbuf 2 x 16K; epilogue C-tile aliases
    const int t = threadIdx.x;          // 0..511
    const int l = t & 63;
    const int wave = t >> 6;            // 0..7
    const int wm = wave >> 2;           // 0..1  (64 m-rows each)
    const int wn = wave & 3;            // 0..3  (32 packed cols each)

    // XCD-aware remap (R8-proven, bijective for 512 = 8*64)
    const int b = blockIdx.x;
    const int xcd = b & 7;
    const int slot = b >> 3;            // 0..63
    const int mt = ((xcd & 1) << 3) + (slot & 7);    // 0..15
    const int nt = ((xcd >> 1) << 3) + (slot >> 3);  // 0..31
    const int m0 = mt * 128;
    const int n0 = nt * 128;

    v4i acc[4][2];
    #pragma unroll
    for (int i = 0; i < 4; ++i)
        #pragma unroll
        for (int j = 0; j < 2; ++j)
            acc[i][j] = (v4i)0;

    // A staging: thread t covers rows {srow, srow+64}, chunk-slot t&7.
    // LDS slot (r, s) holds global chunk s ^ (r&7); (srow+64)&7 == srow&7.
    const int srow = t >> 3;                      // 0..63
    const int schunk = (t & 7) ^ (srow & 7);
    const int8_t* gA = Xhq + (size_t)(m0 + srow) * K_DIM + schunk * 16;
    // B fragment base: col-group (n0>>4) + wn*2 (+nf), lane offset l*16.
    const int8_t* gBf = Wq2 + (((size_t)(n0 >> 4) + wn * 2) << 15) + (size_t)l * 16;

#define STAGE_A(p, kt) do { \
    char* Ad_ = raw + (p) * 16384; \
    _Pragma("unroll") \
    for (int i_ = 0; i_ < 2; ++i_) \
        __builtin_amdgcn_global_load_lds( \
            (const __attribute__((address_space(1))) uint32_t*)(gA + (size_t)(i_ * 64) * K_DIM + (kt) * 128), \
            (__attribute__((address_space(3))) uint32_t*)(Ad_ + i_ * 8192 + t * 16), 16, 0, 0); \
} while (0)

    // B-frag load for tile kt: chunk c = kt*2 + kk, group +nf. 4 x 1KB coalesced.
#define LOADB(dst, kt) do { \
    _Pragma("unroll") \
    for (int kk_ = 0; kk_ < 2; ++kk_) \
        _Pragma("unroll") \
        for (int nf_ = 0; nf_ < 2; ++nf_) \
            dst[kk_][nf_] = *(const v4i*)(gBf + ((size_t)nf_ << 15) + (size_t)((kt) * 2 + kk_) * 1024); \
} while (0)

    v4i bA[2][2], bB[2][2];
    STAGE_A(0, 0);
    LOADB(bA, 0);

    const int rrow = l & 15;
    const int lx = l & 7;   // == r&7 for all fragment rows
    const int g4 = l >> 4;  // 0..3

    // One iteration: identical sync structure to R8 (vmcnt before lead
    // barrier, lgkmcnt(0)+barrier after reads), B in registers.
#define ITER(kt, BU, BL) do { \
    const int p_ = (kt) & 1; \
    if ((kt) < 15) { \
        STAGE_A(p_ ^ 1, (kt) + 1); \
        LOADB(BL, (kt) + 1); \
        asm volatile("s_waitcnt vmcnt(6)" ::: "memory"); \
    } else { \
        asm volatile("s_waitcnt vmcnt(0)" ::: "memory"); \
    } \
    asm volatile("s_barrier" ::: "memory"); \
    const char* As_ = raw + p_ * 16384; \
    v4i a_[2][4]; \
    _Pragma("unroll") \
    for (int kk = 0; kk < 2; ++kk) { \
        const int sl_ = ((kk * 4 + g4) ^ lx) * 16; \
        _Pragma("unroll") \
        for (int mf = 0; mf < 4; ++mf) \
            a_[kk][mf] = *(const v4i*)(As_ + (wm * 64 + mf * 16 + rrow) * 128 + sl_); \
    } \
    _Pragma("unroll") \
    for (int kk = 0; kk < 2; ++kk) \
        _Pragma("unroll") \
        for (int mf = 0; mf < 4; ++mf) \
            _Pragma("unroll") \
            for (int nf = 0; nf < 2; ++nf) \
                acc[mf][nf] = __builtin_amdgcn_mfma_i32_16x16x64_i8( \
                    a_[kk][mf], BU[kk][nf], acc[mf][nf], 0, 0, 0); \
    asm volatile("s_waitcnt lgkmcnt(0)" ::: "memory"); \
    asm volatile("s_barrier" ::: "memory"); \
} while (0)

    for (int k2 = 0; k2 < 8; ++k2) {
        ITER(2 * k2,     bA, bB);
        ITER(2 * k2 + 1, bB, bA);
    }

#undef STAGE_A
#undef LOADB
#undef ITER

    // Epilogue (R8-proven verbatim): two 64-row halves through an LDS C-tile.
    float (*Cs)[132] = (float(*)[132])raw;   // [64][132] f32 = 33792 B
    const float sc = 0.0009765625f;          // 2^-10
    for (int half = 0; half < 2; ++half) {
        __syncthreads();
        if (wm == half) {
            #pragma unroll
            for (int mf = 0; mf < 4; ++mf) {
                const int rb = mf * 16 + ((l >> 4) << 2);
                #pragma unroll
                for (int nf = 0; nf < 2; ++nf) {
                    const int col = wn * 32 + nf * 16 + (l & 15);
                    #pragma unroll
                    for (int rr = 0; rr < 4; ++rr)
                        Cs[rb + rr][col] = (float)acc[mf][nf][rr] * sc;
                }
            }
        }
        __syncthreads();
        #pragma unroll
        for (int it = 0; it < 4; ++it) {
            const int idx = it * 512 + t;        // 0..2047 = 64 rows x 32 j
            const int row = idx >> 5;
            const int jl = idx & 31;
            float4 y = *(const float4*)&Cs[row][jl << 2];
            float4 bb = *(const float4*)&bqp[n0 + (jl << 2)];
            const int m = m0 + half * 64 + row;
            const int j = (n0 >> 2) + jl;
            const float ig = fqf(fsigm(y.x + bb.x));
            const float fg = fqf(fsigm(y.y + bb.y));
            const float gg = fqf(ftanh(y.z + bb.z));
            const float og = fqf(fsigm(y.w + bb.w));
            const float cq = fqf(cin[(size_t)m * 1024 + j]);
            const float cn = cq * fg + ig * gg;
            const float hn = fqf(ftanh(cn)) * og;
            hout[(size_t)m * 1024 + j] = hn;
            cout_[(size_t)m * 1024 + j] = cn;
        }
    }
}

extern "C" void kernel_launch(void* const* d_in, const int* in_sizes, int n_in,
                              void* d_out, int out_size, void* d_ws, size_t ws_size,
                              hipStream_t stream) {
    const float* X    = (const float*)d_in[0];   // [2048,1024]
    const float* h    = (const float*)d_in[1];   // [2048,1024]
    const float* c    = (const float*)d_in[2];   // [2048,1024]
    const float* W    = (const float*)d_in[3];   // [4096,2048]
    const float* bias = (const float*)d_in[4];   // [4096]

    float* out   = (float*)d_out;
    float* h_out = out;                          // [2048,1024]
    float* c_out = out + (size_t)B_DIM * 1024;   // [2048,1024]

    char* ws = (char*)d_ws;
    int8_t* Xhq = (int8_t*)ws;                              // 4 MB
    int8_t* Wq2 = (int8_t*)(ws + (size_t)4 * 1024 * 1024);  // 8 MB (fragment-packed)
    float*  bqp = (float*)(ws + (size_t)12 * 1024 * 1024);  // 16 KB

    quant_pack<<<1281, 256, 0, stream>>>(X, h, W, bias, Xhq, Wq2, bqp);

    lstm_gemm<<<512, 512, 0, stream>>>(Xhq, Wq2, bqp, c, h_out, c_out);
}

// Round 9
// 40.597 us; speedup vs baseline: 1.0792x; 1.0792x over previous
//
#include <hip/hip_runtime.h>
#include <stdint.h>

#define B_DIM 2048
#define K_DIM 2048
#define N_PACK 4096

typedef int v4i __attribute__((ext_vector_type(4)));

__device__ __forceinline__ float fqf(float x) {
    float q = rintf(x * 32.0f);
    q = fminf(fmaxf(q, -128.0f), 127.0f);
    return q * 0.03125f;
}
__device__ __forceinline__ int q8i(float x) {
    float q = rintf(x * 32.0f);
    q = fminf(fmaxf(q, -128.0f), 127.0f);
    return (int)q;
}
// fast sigmoid/tanh: v_exp_f32 + fast div; saturate gracefully at +-inf.
__device__ __forceinline__ float fsigm(float x) {
    return __fdividef(1.0f, 1.0f + __expf(-x));
}
__device__ __forceinline__ float ftanh(float x) {
    return __fdividef(2.0f, 1.0f + __expf(-2.0f * x)) - 1.0f;
}

// One kernel quantizes everything. R15-proven (session best, 40.72 us):
// 16 elements/thread -> 16B/lane stores (full-width coalescing).
//  blocks [0, 1024)        : Xh rows 2b,2b+1 -> Xhq[m][k] int8 (k<1024 X, else h)
//  blocks [1024, 3072)     : W rows         -> Wq[p][k] int8, packed p = j*4 + gate
//  block  3072             : bias           -> bqp[j*4 + gate] (fake-quantized f32)
__global__ __launch_bounds__(256) void quant_pack(
    const float* __restrict__ X, const float* __restrict__ hI,
    const float* __restrict__ W, const float* __restrict__ bias,
    int8_t* __restrict__ Xhq, int8_t* __restrict__ Wq, float* __restrict__ bqp)
{
    const int bid = blockIdx.x;
    const int t = threadIdx.x;
    if (bid < 1024) {
        const int m = bid * 2 + (t >> 7);        // 2 rows per block
        const int k0 = (t & 127) * 16;           // 1024%16==0: never straddles X/h
        const float* src = (k0 < 1024) ? (X + (size_t)m * 1024 + k0)
                                       : (hI + (size_t)m * 1024 + (k0 - 1024));
        float4 v0 = *(const float4*)src;
        float4 v1 = *(const float4*)(src + 4);
        float4 v2 = *(const float4*)(src + 8);
        float4 v3 = *(const float4*)(src + 12);
        union { int8_t c[16]; v4i q; } u;
        u.c[0]  = (int8_t)q8i(v0.x); u.c[1]  = (int8_t)q8i(v0.y);
        u.c[2]  = (int8_t)q8i(v0.z); u.c[3]  = (int8_t)q8i(v0.w);
        u.c[4]  = (int8_t)q8i(v1.x); u.c[5]  = (int8_t)q8i(v1.y);
        u.c[6]  = (int8_t)q8i(v1.z); u.c[7]  = (int8_t)q8i(v1.w);
        u.c[8]  = (int8_t)q8i(v2.x); u.c[9]  = (int8_t)q8i(v2.y);
        u.c[10] = (int8_t)q8i(v2.z); u.c[11] = (int8_t)q8i(v2.w);
        u.c[12] = (int8_t)q8i(v3.x); u.c[13] = (int8_t)q8i(v3.y);
        u.c[14] = (int8_t)q8i(v3.z); u.c[15] = (int8_t)q8i(v3.w);
        *(v4i*)(Xhq + (size_t)m * K_DIM + k0) = u.q;
    } else if (bid < 3072) {
        const int r = (bid - 1024) * 2 + (t >> 7);  // original weight row (gate*1024 + j)
        const int gate = r >> 10, j = r & 1023;
        const int p = (j << 2) | gate;              // packed row
        const int k0 = (t & 127) * 16;
        const float* src = W + (size_t)r * K_DIM + k0;
        float4 v0 = *(const float4*)src;
        float4 v1 = *(const float4*)(src + 4);
        float4 v2 = *(const float4*)(src + 8);
        float4 v3 = *(const float4*)(src + 12);
        union { int8_t c[16]; v4i q; } u;
        u.c[0]  = (int8_t)q8i(v0.x); u.c[1]  = (int8_t)q8i(v0.y);
        u.c[2]  = (int8_t)q8i(v0.z); u.c[3]  = (int8_t)q8i(v0.w);
        u.c[4]  = (int8_t)q8i(v1.x); u.c[5]  = (int8_t)q8i(v1.y);
        u.c[6]  = (int8_t)q8i(v1.z); u.c[7]  = (int8_t)q8i(v1.w);
        u.c[8]  = (int8_t)q8i(v2.x); u.c[9]  = (int8_t)q8i(v2.y);
        u.c[10] = (int8_t)q8i(v2.z); u.c[11] = (int8_t)q8i(v2.w);
        u.c[12] = (int8_t)q8i(v3.x); u.c[13] = (int8_t)q8i(v3.y);
        u.c[14] = (int8_t)q8i(v3.z); u.c[15] = (int8_t)q8i(v3.w);
        *(v4i*)(Wq + (size_t)p * K_DIM + k0) = u.q;
    } else {
        for (int idx = t; idx < N_PACK; idx += 256) {
            const int gate = idx >> 10, j = idx & 1023;
            bqp[(j << 2) | gate] = fqf(bias[idx]);
        }
    }
}

// GEMM C[2048][4096p] = Xhq @ Wq^T (int8 -> i32, exact), fused LSTM epilogue.
// R17 = R8/R15 VERBATIM — the measured session optimum (40.72 us total).
// Eight structural experiments (R9-R16) established: GEMM interval is pinned
// at ~4500 cyc per 64-KB-staged K-step by the VMEM->LDS delivery path
// (~15 B/cyc/CU effective), invariant to barrier count (8/16/32), prefetch
// depth (1/2/3), LDS read/write volume (-33%/-50% tested), wave-tile shape,
// B-from-global, and staged-byte totals (256 vs 192 MB). Requirement for
// the fast regime: >=2 schedulable entities per SIMD (2 blocks/CU here).
// 1-D grid of 512; block b -> xcd = b%8 (HW round-robin), slot = b/8;
// each XCD owns an 8x8 (m,n) sub-grid -> 4MB working set = one XCD L2.
// LDS chunk swizzle (proven 0-conflict): LDS[r][s] holds chunk s ^ (r&7).
__global__ __launch_bounds__(512) void lstm_gemm(
    const int8_t* __restrict__ Xhq, const int8_t* __restrict__ Wq,
    const float* __restrict__ bqp, const float* __restrict__ cin,
    float* __restrict__ hout, float* __restrict__ cout_)
{
    __shared__ __align__(16) char raw[65536];   // 2 x (A 16K + B 16K); epilogue aliases
    const int t = threadIdx.x;          // 0..511
    const int l = t & 63;
    const int wave = t >> 6;            // 0..7
    const int wm = wave >> 2;           // 0..1  (64 m-rows each)
    const int wn = wave & 3;            // 0..3  (32 packed cols each)

    const int b = blockIdx.x;
    const int xcd = b & 7;
    const int slot = b >> 3;            // 0..63
    const int mt = ((xcd & 1) << 3) + (slot & 7);    // 0..15
    const int nt = ((xcd >> 1) << 3) + (slot >> 3);  // 0..31
    const int m0 = mt * 128;
    const int n0 = nt * 128;

    v4i acc[4][2];
    #pragma unroll
    for (int i = 0; i < 4; ++i)
        #pragma unroll
        for (int j = 0; j < 2; ++j)
            acc[i][j] = (v4i)0;

    // staging: thread t covers rows {srow, srow+64}, slot t&7.
    // LDS slot (r, s) holds global chunk s ^ (r&7); (srow+64)&7 == srow&7.
    const int srow = t >> 3;                      // 0..63
    const int schunk = (t & 7) ^ (srow & 7);
    const int8_t* gA = Xhq + (size_t)(m0 + srow) * K_DIM + schunk * 16;
    const int8_t* gB = Wq  + (size_t)(n0 + srow) * K_DIM + schunk * 16;

    const int rrow = l & 15;
    const int lx = l & 7;   // == r&7 for all fragment rows

#define STAGE(p, kt) do { \
    char* Ad_ = raw + (p) * 32768; \
    char* Bd_ = raw + (p) * 32768 + 16384; \
    _Pragma("unroll") \
    for (int i_ = 0; i_ < 2; ++i_) { \
        __builtin_amdgcn_global_load_lds( \
            (const __attribute__((address_space(1))) uint32_t*)(gA + (size_t)(i_ * 64) * K_DIM + (kt) * 128), \
            (__attribute__((address_space(3))) uint32_t*)(Ad_ + i_ * 8192 + t * 16), 16, 0, 0); \
        __builtin_amdgcn_global_load_lds( \
            (const __attribute__((address_space(1))) uint32_t*)(gB + (size_t)(i_ * 64) * K_DIM + (kt) * 128), \
            (__attribute__((address_space(3))) uint32_t*)(Bd_ + i_ * 8192 + t * 16), 16, 0, 0); \
    } \
} while (0)

    STAGE(0, 0);

    for (int kt = 0; kt < 16; ++kt) {
        const int p = kt & 1;
        if (kt < 15) {
            STAGE(p ^ 1, kt + 1);
            asm volatile("s_waitcnt vmcnt(4)" ::: "memory");  // tile kt landed; kt+1 in flight
        } else {
            asm volatile("s_waitcnt vmcnt(0)" ::: "memory");
        }
        asm volatile("s_barrier" ::: "memory");

        const char* As = raw + p * 32768;
        const char* Bs = raw + p * 32768 + 16384;
        v4i a[2][4], b2[2][2];
        #pragma unroll
        for (int kk = 0; kk < 2; ++kk) {
            const int c = kk * 4 + (l >> 4);
            const int sl = (c ^ lx) * 16;
            #pragma unroll
            for (int mf = 0; mf < 4; ++mf) {
                const int r = wm * 64 + mf * 16 + rrow;
                a[kk][mf] = *(const v4i*)(As + r * 128 + sl);
            }
            #pragma unroll
            for (int nf = 0; nf < 2; ++nf) {
                const int r = wn * 32 + nf * 16 + rrow;
                b2[kk][nf] = *(const v4i*)(Bs + r * 128 + sl);
            }
        }
        #pragma unroll
        for (int kk = 0; kk < 2; ++kk)
            #pragma unroll
            for (int mf = 0; mf < 4; ++mf)
                #pragma unroll
                for (int nf = 0; nf < 2; ++nf)
                    acc[mf][nf] = __builtin_amdgcn_mfma_i32_16x16x64_i8(a[kk][mf], b2[kk][nf], acc[mf][nf], 0, 0, 0);
        asm volatile("s_waitcnt lgkmcnt(0)" ::: "memory");   // LDS reads done before overwrite
        asm volatile("s_barrier" ::: "memory");
    }

    // Epilogue: two 64-row halves through an LDS C-tile (aliases staging bufs).
    float (*Cs)[132] = (float(*)[132])raw;   // [64][132] f32 = 33792 B
    const float sc = 0.0009765625f;          // 2^-10
    for (int half = 0; half < 2; ++half) {
        __syncthreads();
        if (wm == half) {
            #pragma unroll
            for (int mf = 0; mf < 4; ++mf) {
                const int rb = mf * 16 + ((l >> 4) << 2);
                #pragma unroll
                for (int nf = 0; nf < 2; ++nf) {
                    const int col = wn * 32 + nf * 16 + (l & 15);
                    #pragma unroll
                    for (int rr = 0; rr < 4; ++rr)
                        Cs[rb + rr][col] = (float)acc[mf][nf][rr] * sc;
                }
            }
        }
        __syncthreads();
        #pragma unroll
        for (int it = 0; it < 4; ++it) {
            const int idx = it * 512 + t;        // 0..2047 = 64 rows x 32 j
            const int row = idx >> 5;
            const int jl = idx & 31;
            float4 y = *(const float4*)&Cs[row][jl << 2];
            float4 bb = *(const float4*)&bqp[n0 + (jl << 2)];
            const int m = m0 + half * 64 + row;
            const int j = (n0 >> 2) + jl;
            const float ig = fqf(fsigm(y.x + bb.x));
            const float fg = fqf(fsigm(y.y + bb.y));
            const float gg = fqf(ftanh(y.z + bb.z));
            const float og = fqf(fsigm(y.w + bb.w));
            const float cq = fqf(cin[(size_t)m * 1024 + j]);
            const float cn = cq * fg + ig * gg;
            const float hn = fqf(ftanh(cn)) * og;
            hout[(size_t)m * 1024 + j] = hn;
            cout_[(size_t)m * 1024 + j] = cn;
        }
    }
}

extern "C" void kernel_launch(void* const* d_in, const int* in_sizes, int n_in,
                              void* d_out, int out_size, void* d_ws, size_t ws_size,
                              hipStream_t stream) {
    const float* X    = (const float*)d_in[0];   // [2048,1024]
    const float* h    = (const float*)d_in[1];   // [2048,1024]
    const float* c    = (const float*)d_in[2];   // [2048,1024]
    const float* W    = (const float*)d_in[3];   // [4096,2048]
    const float* bias = (const float*)d_in[4];   // [4096]

    float* out   = (float*)d_out;
    float* h_out = out;                          // [2048,1024]
    float* c_out = out + (size_t)B_DIM * 1024;   // [2048,1024]

    char* ws = (char*)d_ws;
    int8_t* Xhq = (int8_t*)ws;                              // 4 MB
    int8_t* Wq  = (int8_t*)(ws + (size_t)4 * 1024 * 1024);  // 8 MB
    float*  bqp = (float*)(ws + (size_t)12 * 1024 * 1024);  // 16 KB

    quant_pack<<<3073, 256, 0, stream>>>(X, h, W, bias, Xhq, Wq, bqp);

    lstm_gemm<<<512, 512, 0, stream>>>(Xhq, Wq, bqp, c, h_out, c_out);
}